// Round 1
// baseline (9555.428 us; speedup 1.0000x reference)
//
#include <hip/hip_runtime.h>

typedef short bf16x8 __attribute__((ext_vector_type(8)));
typedef float f32x4  __attribute__((ext_vector_type(4)));

constexpr int BB = 64;     // batch
constexpr int TT = 1024;   // seq len
constexpr int DD = 64;     // input dim
constexpr int HH = 512;    // hidden
constexpr int NGRP = 4;    // batch groups
constexpr int WPG  = 16;   // workgroups per group (each owns 32 hidden units)
constexpr int MB   = 16;   // batch rows per group
constexpr int UPW  = 32;   // hidden units per wg
constexpr int BLOCK = 384; // 6 waves

// ws layout: board [2][NGRP][16 kk][64 lane][8] shorts, then barrier counters
constexpr size_t BOARD_SHORTS = (size_t)2 * NGRP * 16 * 64 * 8;   // 65536 shorts
constexpr size_t BAR_OFF      = BOARD_SHORTS * sizeof(short);     // 131072 B

__device__ __forceinline__ short f2bf(float f) {
    unsigned u = __builtin_bit_cast(unsigned, f);
    u = (u + 0x7FFFu + ((u >> 16) & 1u)) >> 16;   // round-to-nearest-even
    return (short)u;
}
__device__ __forceinline__ float bf2f(short s) {
    unsigned u = ((unsigned)(unsigned short)s) << 16;
    return __builtin_bit_cast(float, u);
}

__global__ __launch_bounds__(BLOCK, 2)
void gru_persistent(const float* __restrict__ x,
                    const float* __restrict__ h0,
                    const float* __restrict__ w_ih,
                    const float* __restrict__ w_hh,
                    const float* __restrict__ fc_w,
                    const float* __restrict__ fc_b,
                    float* __restrict__ out,
                    short* __restrict__ board,
                    int* __restrict__ bar)
{
    const int wg   = blockIdx.x;     // 0..63
    const int gb   = wg >> 4;        // batch group 0..3
    const int wid  = wg & 15;        // unit-wg 0..15 (owns kk block == wid)
    const int tid  = threadIdx.x;
    const int wave = tid >> 6;       // 0..5
    const int lane = tid & 63;
    const int l15  = lane & 15;
    const int lhi  = lane >> 4;      // 0..3
    const int u0   = wid * UPW;

    // wave's 16 gate columns (local cols [16*wave, 16*wave+16) of 96 = r|z|n x 32)
    const int cloc = wave * 16 + l15;       // 0..95
    const int gate = cloc >> 5;             // 0=r 1=z 2=n
    const int uloc = cloc & 31;
    const int grow = gate * HH + u0 + uloc; // row of w_hh / w_ih

    __shared__ float lds_gi[16][100];
    __shared__ float lds_gh[16][100];
    __shared__ float hprev[512];   // f32 h state for this wg's units: [uu*16+row]
    __shared__ float pacc[512];
    __shared__ float fcw_s[UPW];

    // ---- register-resident weights as MFMA B-fragments, bf16 hi/lo split ----
    // B-frag layout for 16x16x32: col = lane&15, k = (lane>>4)*8 + i
    bf16x8 whh_hi[16], whh_lo[16];
#pragma unroll
    for (int kk = 0; kk < 16; ++kk) {
        const float* src = w_hh + (size_t)grow * HH + kk * 32 + lhi * 8;
        bf16x8 hi, lo;
#pragma unroll
        for (int i = 0; i < 8; ++i) {
            float w = src[i];
            short h16 = f2bf(w);
            hi[i] = h16;
            lo[i] = f2bf(w - bf2f(h16));
        }
        whh_hi[kk] = hi; whh_lo[kk] = lo;
    }
    bf16x8 wih_hi[2], wih_lo[2];
#pragma unroll
    for (int kk = 0; kk < 2; ++kk) {
        const float* src = w_ih + (size_t)grow * DD + kk * 32 + lhi * 8;
        bf16x8 hi, lo;
#pragma unroll
        for (int i = 0; i < 8; ++i) {
            float w = src[i];
            short h16 = f2bf(w);
            hi[i] = h16;
            lo[i] = f2bf(w - bf2f(h16));
        }
        wih_hi[kk] = hi; wih_lo[kk] = lo;
    }

    if (tid < UPW) fcw_s[tid] = fc_w[u0 + tid];

    // ---- init h state: hprev (f32) + board buf0 in A-frag layout ----
    for (int idx = tid; idx < 512; idx += BLOCK) {
        int uu = idx >> 4, row = idx & 15;
        float hv = h0[(size_t)(gb * MB + row) * HH + (u0 + uu)];
        hprev[idx] = hv;
        board[((size_t)(0 * NGRP + gb) * 16 + wid) * 512
              + (row + 16 * (uu >> 3)) * 8 + (uu & 7)] = f2bf(hv);
    }

    const float fcb = fc_b[0];
    int epoch = 0;

    // group-local barrier over WPG wgs (monotonic counter, agent-scope fences)
    auto gbar = [&]() {
        __syncthreads();
        __builtin_amdgcn_fence(__ATOMIC_RELEASE, "agent");
        ++epoch;
        if (tid == 0) {
            __hip_atomic_fetch_add(&bar[gb], 1, __ATOMIC_RELAXED, __HIP_MEMORY_SCOPE_AGENT);
            while (__hip_atomic_load(&bar[gb], __ATOMIC_RELAXED, __HIP_MEMORY_SCOPE_AGENT)
                   < epoch * WPG) {
                __builtin_amdgcn_s_sleep(2);
            }
        }
        __builtin_amdgcn_fence(__ATOMIC_ACQUIRE, "agent");
        __syncthreads();
    };

    gbar();  // make h0 board visible group-wide

    for (int t = 0; t < TT; ++t) {
        const int rbuf = t & 1, wbuf = rbuf ^ 1;

        f32x4 acc_gi = {0.f, 0.f, 0.f, 0.f};
        f32x4 acc_gh = {0.f, 0.f, 0.f, 0.f};

        // gi = x_t @ w_ih^T   (A row = batch row l15, k = input dim)
#pragma unroll
        for (int kk = 0; kk < 2; ++kk) {
            const float* xs = x + ((size_t)(gb * MB + l15) * TT + t) * DD + kk * 32 + lhi * 8;
            const float4 v0 = *(const float4*)(xs);
            const float4 v1 = *(const float4*)(xs + 4);
            bf16x8 a;
            a[0] = f2bf(v0.x); a[1] = f2bf(v0.y); a[2] = f2bf(v0.z); a[3] = f2bf(v0.w);
            a[4] = f2bf(v1.x); a[5] = f2bf(v1.y); a[6] = f2bf(v1.z); a[7] = f2bf(v1.w);
            acc_gi = __builtin_amdgcn_mfma_f32_16x16x32_bf16(a, wih_hi[kk], acc_gi, 0, 0, 0);
            acc_gi = __builtin_amdgcn_mfma_f32_16x16x32_bf16(a, wih_lo[kk], acc_gi, 0, 0, 0);
        }

        // gh = h_t @ w_hh^T  (board already stored in A-frag layout)
        const short* bd = board + (size_t)(rbuf * NGRP + gb) * 16 * 512 + lane * 8;
#pragma unroll
        for (int kk = 0; kk < 16; ++kk) {
            bf16x8 a = *(const bf16x8*)(bd + (size_t)kk * 512);
            acc_gh = __builtin_amdgcn_mfma_f32_16x16x32_bf16(a, whh_hi[kk], acc_gh, 0, 0, 0);
            acc_gh = __builtin_amdgcn_mfma_f32_16x16x32_bf16(a, whh_lo[kk], acc_gh, 0, 0, 0);
        }

        // C/D layout: col = lane&15, row = (lane>>4)*4 + j
#pragma unroll
        for (int j = 0; j < 4; ++j) {
            int row = lhi * 4 + j;
            lds_gi[row][cloc] = acc_gi[j];
            lds_gh[row][cloc] = acc_gh[j];
        }
        __syncthreads();

        // gates + h update + fused fc partial
        for (int idx = tid; idx < 512; idx += BLOCK) {
            int uu = idx >> 4, row = idx & 15;
            float gr  = lds_gi[row][uu]      + lds_gh[row][uu];
            float gz  = lds_gi[row][32 + uu] + lds_gh[row][32 + uu];
            float gin = lds_gi[row][64 + uu];
            float ghn = lds_gh[row][64 + uu];
            float r = 1.f / (1.f + __expf(-gr));
            float z = 1.f / (1.f + __expf(-gz));
            float v = gin + r * ghn;
            v = fminf(15.f, fmaxf(-15.f, v));
            float e2 = __expf(-2.f * v);
            float n = (1.f - e2) / (1.f + e2);           // tanh(v)
            float hn = (1.f - z) * n + z * hprev[idx];
            hprev[idx] = hn;
            board[((size_t)(wbuf * NGRP + gb) * 16 + wid) * 512
                  + (row + 16 * (uu >> 3)) * 8 + (uu & 7)] = f2bf(hn);
            if (t == TT - 1)
                out[(size_t)BB * TT + (size_t)(gb * MB + row) * HH + (u0 + uu)] = hn;
            pacc[idx] = fmaxf(hn, 0.f) * fcw_s[uu];
        }
        __syncthreads();

        if (tid < MB) {
            float s = (wid == 0) ? fcb : 0.f;
#pragma unroll
            for (int uu = 0; uu < UPW; ++uu) s += pacc[uu * 16 + tid];
            atomicAdd(&out[(size_t)(gb * MB + tid) * TT + t], s);
        }

        gbar();
    }
}

extern "C" void kernel_launch(void* const* d_in, const int* in_sizes, int n_in,
                              void* d_out, int out_size, void* d_ws, size_t ws_size,
                              hipStream_t stream)
{
    const float* x    = (const float*)d_in[0];
    const float* h0   = (const float*)d_in[1];
    const float* w_ih = (const float*)d_in[2];
    const float* w_hh = (const float*)d_in[3];
    const float* fc_w = (const float*)d_in[4];
    const float* fc_b = (const float*)d_in[5];
    float* out   = (float*)d_out;
    short* board = (short*)d_ws;
    int*   bar   = (int*)((char*)d_ws + BAR_OFF);

    // zero the atomically-accumulated out region + board/barrier scratch
    hipMemsetAsync(d_out, 0, (size_t)BB * TT * sizeof(float), stream);
    hipMemsetAsync(d_ws, 0, BAR_OFF + 64, stream);

    void* args[] = { (void*)&x, (void*)&h0, (void*)&w_ih, (void*)&w_hh,
                     (void*)&fc_w, (void*)&fc_b, (void*)&out, (void*)&board, (void*)&bar };
    hipLaunchCooperativeKernel((void*)gru_persistent, dim3(NGRP * WPG), dim3(BLOCK),
                               args, 0, stream);
}

// Round 2
// 4253.707 us; speedup vs baseline: 2.2464x; 2.2464x over previous
//
#include <hip/hip_runtime.h>

typedef short bf16x8 __attribute__((ext_vector_type(8)));
typedef float f32x4  __attribute__((ext_vector_type(4)));
typedef unsigned long long u64;

constexpr int BB = 64;     // batch
constexpr int TT = 1024;   // seq len
constexpr int DD = 64;     // input dim
constexpr int HH = 512;    // hidden
constexpr int NGRP = 4;    // batch groups
constexpr int WPG  = 16;   // workgroups per group (each owns 32 hidden units)
constexpr int MB   = 16;   // batch rows per group
constexpr int UPW  = 32;   // hidden units per wg
constexpr int BLOCK = 384; // 6 waves

// ws layout: board [2][NGRP][WPG][256] ints (A-frag layout, bf16 pairs), then flags
constexpr size_t BOARD_INTS = (size_t)2 * NGRP * WPG * 256;   // 32768 ints = 128 KB
constexpr size_t FLAGS_OFF  = BOARD_INTS * sizeof(int);       // 131072 B

__device__ __forceinline__ short f2bf(float f) {
    unsigned u = __builtin_bit_cast(unsigned, f);
    u = (u + 0x7FFFu + ((u >> 16) & 1u)) >> 16;   // round-to-nearest-even
    return (short)u;
}
__device__ __forceinline__ float bf2f(short s) {
    unsigned u = ((unsigned)(unsigned short)s) << 16;
    return __builtin_bit_cast(float, u);
}
__device__ __forceinline__ int pack2(float a, float b) {
    return (int)(unsigned short)f2bf(a) | ((int)(unsigned short)f2bf(b) << 16);
}

__global__ __launch_bounds__(BLOCK, 1)
void gru_persistent(const float* __restrict__ x,
                    const float* __restrict__ h0,
                    const float* __restrict__ w_ih,
                    const float* __restrict__ w_hh,
                    const float* __restrict__ fc_w,
                    const float* __restrict__ fc_b,
                    float* __restrict__ out,
                    int* __restrict__ board,
                    int* __restrict__ flags)
{
    const int wg   = blockIdx.x;     // 0..63
    const int gb   = wg >> 4;        // batch group 0..3
    const int wid  = wg & 15;        // unit-wg 0..15 (owns k-block == wid)
    const int tid  = threadIdx.x;
    const int wave = tid >> 6;       // 0..5
    const int lane = tid & 63;
    const int l15  = lane & 15;
    const int lhi  = lane >> 4;      // 0..3
    const int u0   = wid * UPW;

    // wave's 16 gate columns (local cols [16*wave, 16*wave+16) of 96 = r|z|n x 32)
    const int cloc = wave * 16 + l15;       // 0..95
    const int gate = cloc >> 5;             // 0=r 1=z 2=n
    const int uloc = cloc & 31;
    const int grow = gate * HH + u0 + uloc; // row of w_hh / w_ih

    __shared__ float lds_gi[16][100];
    __shared__ float lds_gh[16][100];
    __shared__ float hprev[512];   // f32 h state for this wg's units: [uu*16+row]
    __shared__ float pacc[512];
    __shared__ float fcw_s[UPW];

    // ---- register-resident weights as MFMA B-fragments, bf16 hi/lo split ----
    // B-frag layout for 16x16x32: col = lane&15, k = (lane>>4)*8 + i
    bf16x8 whh_hi[16], whh_lo[16];
#pragma unroll
    for (int kk = 0; kk < 16; ++kk) {
        const float* src = w_hh + (size_t)grow * HH + kk * 32 + lhi * 8;
        bf16x8 hi, lo;
#pragma unroll
        for (int i = 0; i < 8; ++i) {
            float w = src[i];
            short h16 = f2bf(w);
            hi[i] = h16;
            lo[i] = f2bf(w - bf2f(h16));
        }
        whh_hi[kk] = hi; whh_lo[kk] = lo;
    }
    bf16x8 wih_hi[2], wih_lo[2];
#pragma unroll
    for (int kk = 0; kk < 2; ++kk) {
        const float* src = w_ih + (size_t)grow * DD + kk * 32 + lhi * 8;
        bf16x8 hi, lo;
#pragma unroll
        for (int i = 0; i < 8; ++i) {
            float w = src[i];
            short h16 = f2bf(w);
            hi[i] = h16;
            lo[i] = f2bf(w - bf2f(h16));
        }
        wih_hi[kk] = hi; wih_lo[kk] = lo;
    }

    if (tid < UPW) fcw_s[tid] = fc_w[u0 + tid];
    const float fcb = fc_b[0];

    // ---- init h state: hprev (f32) + board buf0 (packed bf16 pairs, A-frag layout) ----
    for (int idx2 = tid; idx2 < 256; idx2 += BLOCK) {
        int row = idx2 & 15, up = idx2 >> 4;
        int uu0 = up * 2, uu1 = uu0 + 1;
        float ha = h0[(size_t)(gb * MB + row) * HH + (u0 + uu0)];
        float hb = h0[(size_t)(gb * MB + row) * HH + (u0 + uu1)];
        hprev[uu0 * 16 + row] = ha;
        hprev[uu1 * 16 + row] = hb;
        int bi = ((0 * NGRP + gb) * WPG + wid) * 256 + (row + 16 * (up >> 2)) * 4 + (up & 3);
        __hip_atomic_store(&board[bi], pack2(ha, hb), __ATOMIC_RELAXED, __HIP_MEMORY_SCOPE_AGENT);
    }
    __syncthreads();  // drains vmcnt -> board stores at coherence point
    if (tid == 0)
        __hip_atomic_store(&flags[gb * 16 + wid], 1, __ATOMIC_RELAXED, __HIP_MEMORY_SCOPE_AGENT);

    for (int t = 0; t < TT; ++t) {
        const int rbuf = t & 1, wbuf = rbuf ^ 1;

        // ---- gi = x_t @ w_ih^T : independent of h, compute BEFORE waiting ----
        f32x4 acc_gi = {0.f, 0.f, 0.f, 0.f};
#pragma unroll
        for (int kk = 0; kk < 2; ++kk) {
            const float* xs = x + ((size_t)(gb * MB + l15) * TT + t) * DD + kk * 32 + lhi * 8;
            const float4 v0 = *(const float4*)(xs);
            const float4 v1 = *(const float4*)(xs + 4);
            bf16x8 a;
            a[0] = f2bf(v0.x); a[1] = f2bf(v0.y); a[2] = f2bf(v0.z); a[3] = f2bf(v0.w);
            a[4] = f2bf(v1.x); a[5] = f2bf(v1.y); a[6] = f2bf(v1.z); a[7] = f2bf(v1.w);
            acc_gi = __builtin_amdgcn_mfma_f32_16x16x32_bf16(a, wih_hi[kk], acc_gi, 0, 0, 0);
            acc_gi = __builtin_amdgcn_mfma_f32_16x16x32_bf16(a, wih_lo[kk], acc_gi, 0, 0, 0);
        }

        // ---- wait for h(t): poll the 16 per-WG epoch flags (one cacheline) ----
        {
            const int* fl = &flags[gb * 16 + l15];
            const int target = t + 1;
            while (true) {
                int f = __hip_atomic_load(fl, __ATOMIC_RELAXED, __HIP_MEMORY_SCOPE_AGENT);
                if (__all(f >= target)) break;
            }
            asm volatile("" ::: "memory");
        }

        // ---- stage full board (coherent sc1 loads), then gh MFMAs ----
        const u64* bu = (const u64*)board + ((size_t)(rbuf * NGRP + gb) * WPG) * 128 + lane * 2;
        bf16x8 hf[16];
#pragma unroll
        for (int kk = 0; kk < 16; ++kk) {
            u64 lo = __hip_atomic_load(bu + (size_t)kk * 128,     __ATOMIC_RELAXED, __HIP_MEMORY_SCOPE_AGENT);
            u64 hi = __hip_atomic_load(bu + (size_t)kk * 128 + 1, __ATOMIC_RELAXED, __HIP_MEMORY_SCOPE_AGENT);
            struct U2 { u64 a, b; } p{lo, hi};
            hf[kk] = __builtin_bit_cast(bf16x8, p);
        }
        f32x4 acc_gh = {0.f, 0.f, 0.f, 0.f};
#pragma unroll
        for (int kk = 0; kk < 16; ++kk) {
            acc_gh = __builtin_amdgcn_mfma_f32_16x16x32_bf16(hf[kk], whh_hi[kk], acc_gh, 0, 0, 0);
            acc_gh = __builtin_amdgcn_mfma_f32_16x16x32_bf16(hf[kk], whh_lo[kk], acc_gh, 0, 0, 0);
        }

        // C/D layout: col = lane&15, row = (lane>>4)*4 + j
#pragma unroll
        for (int j = 0; j < 4; ++j) {
            int row = lhi * 4 + j;
            lds_gi[row][cloc] = acc_gi[j];
            lds_gh[row][cloc] = acc_gh[j];
        }
        __syncthreads();

        // ---- gates + h update + board publish (2 units per thread, packed int store) ----
        for (int idx2 = tid; idx2 < 256; idx2 += BLOCK) {
            int row = idx2 & 15, up = idx2 >> 4;
            int uu0 = up * 2, uu1 = uu0 + 1;
            float hn01[2];
#pragma unroll
            for (int q = 0; q < 2; ++q) {
                int uu = uu0 + q;
                float gr  = lds_gi[row][uu]      + lds_gh[row][uu];
                float gz  = lds_gi[row][32 + uu] + lds_gh[row][32 + uu];
                float gin = lds_gi[row][64 + uu];
                float ghn = lds_gh[row][64 + uu];
                float r = 1.f / (1.f + __expf(-gr));
                float z = 1.f / (1.f + __expf(-gz));
                float v = gin + r * ghn;
                v = fminf(15.f, fmaxf(-15.f, v));
                float e2 = __expf(-2.f * v);
                float n = (1.f - e2) / (1.f + e2);           // tanh(v)
                float hn = (1.f - z) * n + z * hprev[uu * 16 + row];
                hprev[uu * 16 + row] = hn;
                pacc[uu * 16 + row] = fmaxf(hn, 0.f) * fcw_s[uu];
                hn01[q] = hn;
            }
            int bi = ((wbuf * NGRP + gb) * WPG + wid) * 256 + (row + 16 * (up >> 2)) * 4 + (up & 3);
            __hip_atomic_store(&board[bi], pack2(hn01[0], hn01[1]),
                               __ATOMIC_RELAXED, __HIP_MEMORY_SCOPE_AGENT);
            if (t == TT - 1) {
                out[(size_t)BB * TT + (size_t)(gb * MB + row) * HH + (u0 + uu0)] = hn01[0];
                out[(size_t)BB * TT + (size_t)(gb * MB + row) * HH + (u0 + uu1)] = hn01[1];
            }
        }
        __syncthreads();  // drains vmcnt -> all board stores at coherence point

        // publish FIRST (critical path), then do the fc reduction off-path
        if (tid == 0)
            __hip_atomic_store(&flags[gb * 16 + wid], t + 2,
                               __ATOMIC_RELAXED, __HIP_MEMORY_SCOPE_AGENT);

        if (tid < MB) {
            float s = (wid == 0) ? fcb : 0.f;
#pragma unroll
            for (int uu = 0; uu < UPW; ++uu) s += pacc[uu * 16 + tid];
            atomicAdd(&out[(size_t)(gb * MB + tid) * TT + t], s);
        }
    }
}

extern "C" void kernel_launch(void* const* d_in, const int* in_sizes, int n_in,
                              void* d_out, int out_size, void* d_ws, size_t ws_size,
                              hipStream_t stream)
{
    const float* x    = (const float*)d_in[0];
    const float* h0   = (const float*)d_in[1];
    const float* w_ih = (const float*)d_in[2];
    const float* w_hh = (const float*)d_in[3];
    const float* fc_w = (const float*)d_in[4];
    const float* fc_b = (const float*)d_in[5];
    float* out  = (float*)d_out;
    int* board  = (int*)d_ws;
    int* flags  = (int*)((char*)d_ws + FLAGS_OFF);

    // zero the atomically-accumulated out region + epoch flags (board is fully
    // overwritten by the kernel before first read)
    hipMemsetAsync(d_out, 0, (size_t)BB * TT * sizeof(float), stream);
    hipMemsetAsync((char*)d_ws + FLAGS_OFF, 0, 512, stream);

    void* args[] = { (void*)&x, (void*)&h0, (void*)&w_ih, (void*)&w_hh,
                     (void*)&fc_w, (void*)&fc_b, (void*)&out, (void*)&board, (void*)&flags };
    hipLaunchCooperativeKernel((void*)gru_persistent, dim3(NGRP * WPG), dim3(BLOCK),
                               args, 0, stream);
}